// Round 1
// baseline (1443.236 us; speedup 1.0000x reference)
//
#include <hip/hip_runtime.h>
#include <math.h>

#define CH   128
#define NSP  4096
#define BATCH 4
#define BIG  (BATCH*NSP*CH)   // 2,097,152 floats per (B,N,C) buffer

// ---------------- LayerNorm over channels → xf (B*N, C) ----------------
__global__ __launch_bounds__(256) void ln_kernel(const float* __restrict__ x,
    const float* __restrict__ g, const float* __restrict__ bta, float* __restrict__ xf) {
  __shared__ float tile[128][65];   // [c][n], +1 pad kills power-of-2 conflicts
  __shared__ float pS[4][64];
  __shared__ float pQ[4][64];
  __shared__ float mu_s[64], rs_s[64];
  int t = threadIdx.x;
  int b  = blockIdx.x >> 6;
  int n0 = (blockIdx.x & 63) << 6;
  for (int i = t; i < 8192; i += 256) {           // coalesced over n
    int c = i >> 6, n = i & 63;
    tile[c][n] = x[(size_t)(b*CH + c)*NSP + n0 + n];
  }
  __syncthreads();
  {
    int n = t & 63, part = t >> 6;
    float s = 0.f, qq = 0.f;
    for (int c = part; c < 128; c += 4) { float v = tile[c][n]; s += v; qq += v*v; }
    pS[part][n] = s; pQ[part][n] = qq;
  }
  __syncthreads();
  if (t < 64) {
    float s = pS[0][t] + pS[1][t] + pS[2][t] + pS[3][t];
    float qq = pQ[0][t] + pQ[1][t] + pQ[2][t] + pQ[3][t];
    float mu = s * (1.f/128.f);
    float var = qq * (1.f/128.f) - mu*mu;
    mu_s[t] = mu;
    rs_s[t] = rsqrtf(var + 1e-5f);
  }
  __syncthreads();
  for (int i = t; i < 8192; i += 256) {           // coalesced over c
    int n = i >> 7, c = i & 127;
    float v = (tile[c][n] - mu_s[n]) * rs_s[n] * g[c] + bta[c];
    xf[(size_t)(b*NSP + n0 + n)*CH + c] = v;
  }
}

// ---------------- pooled = mean_x over spatial → (B,C) ----------------
__global__ __launch_bounds__(256) void pooled_kernel(const float* __restrict__ x,
                                                     float* __restrict__ pooled) {
  int bc = blockIdx.x; int t = threadIdx.x;
  const float4* p = (const float4*)(x + (size_t)bc*NSP);
  float s = 0.f;
  for (int i = t; i < 1024; i += 256) { float4 v = p[i]; s += v.x+v.y+v.z+v.w; }
  for (int off = 32; off; off >>= 1) s += __shfl_xor(s, off, 64);
  __shared__ float red[4];
  if ((t & 63) == 0) red[t >> 6] = s;
  __syncthreads();
  if (t == 0) pooled[bc] = (red[0]+red[1]+red[2]+red[3]) * (1.f/4096.f);
}

// ---------------- gate weights = softmax(pooled @ Wg^T + bg) → (B,3) ----------------
__global__ void gate_kernel(const float* __restrict__ pooled, const float* __restrict__ Wg,
                            const float* __restrict__ bg, float* __restrict__ wgt) {
  __shared__ float lg[4][3];
  int t = threadIdx.x;
  if (t < 12) {
    int b = t / 3, j = t % 3;
    float s = bg[j];
    const float* pr = pooled + b*CH;
    const float* wr = Wg + j*CH;
    for (int c = 0; c < CH; ++c) s += pr[c]*wr[c];
    lg[b][j] = s;
  }
  __syncthreads();
  if (t < 4) {
    float a = lg[t][0], b2 = lg[t][1], c = lg[t][2];
    float m = fmaxf(a, fmaxf(b2, c));
    float e0 = __expf(a-m), e1 = __expf(b2-m), e2 = __expf(c-m);
    float inv = 1.f/(e0+e1+e2);
    wgt[t*3+0] = e0*inv; wgt[t*3+1] = e1*inv; wgt[t*3+2] = e2*inv;
  }
}

// ---------------- Conv3d C->2, k=3, SAME (cross-correlation) ----------------
__global__ __launch_bounds__(256) void conv_kernel(const float* __restrict__ xf,
    const float* __restrict__ Wc, const float* __restrict__ bc_, float* __restrict__ cgf) {
  int gid = blockIdx.x*256 + threadIdx.x;       // 32768 outputs
  int sp = gid & 4095;
  int o  = (gid >> 12) & 1;
  int b  = gid >> 13;
  int z = sp >> 8, y = (sp >> 4) & 15, xw = sp & 15;
  float acc = bc_[o];
  const float* Wo = Wc + o*3456;                // (c,kd,kh,kw): c*27 + kd*9+kh*3+kw
  for (int kd = 0; kd < 3; ++kd) {
    int zz = z + kd - 1; if ((unsigned)zz >= 16u) continue;
    for (int kh = 0; kh < 3; ++kh) {
      int yy = y + kh - 1; if ((unsigned)yy >= 16u) continue;
      for (int kw = 0; kw < 3; ++kw) {
        int xx = xw + kw - 1; if ((unsigned)xx >= 16u) continue;
        int n = (zz << 8) + (yy << 4) + xx;
        const float4* xr = (const float4*)(xf + (size_t)(b*NSP + n)*CH);
        const float* wt = Wo + kd*9 + kh*3 + kw;
        #pragma unroll 8
        for (int c4 = 0; c4 < 32; ++c4) {
          float4 xv = xr[c4];
          int cb = c4*4;
          acc += xv.x*wt[cb*27] + xv.y*wt[(cb+1)*27]
               + xv.z*wt[(cb+2)*27] + xv.w*wt[(cb+3)*27];
        }
      }
    }
  }
  cgf[gid] = acc;
}

// ---------------- 64x128 GEMM tile:  Y[r][o] = sum_k X[r][k]*W[o][k] (+bias) ----------------
__device__ __forceinline__ void gemm_tile_64x128(const float* __restrict__ X, int R0,
    const float* __restrict__ W, const float* __restrict__ bias, float* __restrict__ Y) {
  __shared__ float Xs[64][132];
  int t = threadIdx.x; int tx = t & 15; int ty = t >> 4;
  for (int i = t; i < 2048; i += 256) {          // 64 rows * 32 float4
    int r = i >> 5, c4 = (i & 31) << 2;
    *(float4*)&Xs[r][c4] = *(const float4*)&X[(size_t)(R0 + r)*CH + c4];
  }
  __syncthreads();
  float acc[4][8];
  #pragma unroll
  for (int i = 0; i < 4; ++i)
    #pragma unroll
    for (int m = 0; m < 8; ++m) acc[i][m] = 0.f;
  int o0 = tx*8;
  #pragma unroll 2
  for (int k4 = 0; k4 < 128; k4 += 4) {
    float4 a0 = *(float4*)&Xs[ty     ][k4];
    float4 a1 = *(float4*)&Xs[ty + 16][k4];
    float4 a2 = *(float4*)&Xs[ty + 32][k4];
    float4 a3 = *(float4*)&Xs[ty + 48][k4];
    #pragma unroll
    for (int m = 0; m < 8; ++m) {
      float4 w = *(const float4*)&W[(size_t)(o0+m)*CH + k4];
      acc[0][m] += a0.x*w.x + a0.y*w.y + a0.z*w.z + a0.w*w.w;
      acc[1][m] += a1.x*w.x + a1.y*w.y + a1.z*w.z + a1.w*w.w;
      acc[2][m] += a2.x*w.x + a2.y*w.y + a2.z*w.z + a2.w*w.w;
      acc[3][m] += a3.x*w.x + a3.y*w.y + a3.z*w.z + a3.w*w.w;
    }
  }
  float bs[8];
  #pragma unroll
  for (int m = 0; m < 8; ++m) bs[m] = bias ? bias[o0+m] : 0.f;
  #pragma unroll
  for (int i = 0; i < 4; ++i) {
    size_t r = (size_t)(R0 + ty + 16*i);
    float4 v0 = make_float4(acc[i][0]+bs[0], acc[i][1]+bs[1], acc[i][2]+bs[2], acc[i][3]+bs[3]);
    float4 v1 = make_float4(acc[i][4]+bs[4], acc[i][5]+bs[5], acc[i][6]+bs[6], acc[i][7]+bs[7]);
    *(float4*)&Y[r*CH + o0    ] = v0;
    *(float4*)&Y[r*CH + o0 + 4] = v1;
  }
}

__global__ __launch_bounds__(256) void proj_kernel(const float* __restrict__ xf,
    const float* __restrict__ Wq, const float* __restrict__ bq,
    const float* __restrict__ Wk, const float* __restrict__ bk,
    const float* __restrict__ Wvc, const float* __restrict__ bvc,
    const float* __restrict__ Wvch, const float* __restrict__ bvch,
    float* __restrict__ q, float* __restrict__ k,
    float* __restrict__ vc, float* __restrict__ vch) {
  int R0 = blockIdx.x * 64;
  const float* W; const float* bias; float* Y;
  switch (blockIdx.y) {
    case 0:  W = Wq;   bias = bq;   Y = q;   break;
    case 1:  W = Wk;   bias = bk;   Y = k;   break;
    case 2:  W = Wvc;  bias = bvc;  Y = vc;  break;
    default: W = Wvch; bias = bvch; Y = vch; break;
  }
  gemm_tile_64x128(xf, R0, W, bias, Y);
}

// out_channel[n][c] = sum_d vch[n][d] * A[c][d]  — same tile shape, per-batch W
__global__ __launch_bounds__(256) void chout_kernel(const float* __restrict__ vch,
    const float* __restrict__ A, float* __restrict__ out_ch) {
  int R0 = blockIdx.x * 64;
  int b = blockIdx.x >> 6;
  gemm_tile_64x128(vch, R0, A + (size_t)b*CH*CH, nullptr, out_ch);
}

// ---------------- channel-attention raw scores S[b][c][d] = sum_n q[n][c]k[n][d] ----------------
__global__ __launch_bounds__(256) void chscore_kernel(const float* __restrict__ q,
    const float* __restrict__ k, float* __restrict__ S) {
  int b = blockIdx.x >> 4, ct = blockIdx.x & 15;
  int t = threadIdx.x;
  int d = t & 127, cg = t >> 7;
  int cb = ct*8 + cg*4;
  const float* qb = q + (size_t)b*NSP*CH;
  const float* kb = k + (size_t)b*NSP*CH;
  float a0=0.f, a1=0.f, a2=0.f, a3=0.f;
  for (int n = 0; n < NSP; n += 2) {
    float kv0 = kb[(size_t)n*CH + d];
    float kv1 = kb[(size_t)(n+1)*CH + d];
    const float* q0 = qb + (size_t)n*CH + cb;
    const float* q1 = q0 + CH;
    a0 += q0[0]*kv0 + q1[0]*kv1;
    a1 += q0[1]*kv0 + q1[1]*kv1;
    a2 += q0[2]*kv0 + q1[2]*kv1;
    a3 += q0[3]*kv0 + q1[3]*kv1;
  }
  float* Sr = S + ((size_t)b*CH + cb)*CH + d;
  Sr[0]    = a0;
  Sr[CH]   = a1;
  Sr[2*CH] = a2;
  Sr[3*CH] = a3;
}

// softmax over last axis of (B*C, 128), scale 1/sqrt(N)=1/64, in place
__global__ __launch_bounds__(64) void chsoftmax_kernel(float* __restrict__ S) {
  int row = blockIdx.x; int t = threadIdx.x;
  float* r = S + (size_t)row*CH;
  const float sc = 1.f/64.f;
  float s0 = r[t]*sc, s1 = r[t+64]*sc;
  float m = fmaxf(s0, s1);
  for (int off = 32; off; off >>= 1) m = fmaxf(m, __shfl_xor(m, off, 64));
  float p0 = __expf(s0 - m), p1 = __expf(s1 - m);
  float s = p0 + p1;
  for (int off = 32; off; off >>= 1) s += __shfl_xor(s, off, 64);
  float inv = 1.f/s;
  r[t]    = p0*inv;
  r[t+64] = p1*inv;
}

// ---------------- flash attention (full softmax over 4096): 32-row Q tiles ----------------
__global__ __launch_bounds__(256) void flash_kernel(const float* __restrict__ Qg,
    const float* __restrict__ Kg, const float* __restrict__ Vg, float* __restrict__ Og) {
  __shared__ float Qs[32][132];
  __shared__ float Ks[32][132];
  __shared__ float Vs[32][128];
  __shared__ float Ss[32][37];
  __shared__ float mrow[32], lrow[32], arow[32];
  int t = threadIdx.x; int tx = t & 15; int ty = t >> 4;
  int b  = blockIdx.x >> 7;
  int n0 = (blockIdx.x & 127) << 5;
  const float* Q = Qg + (size_t)b*NSP*CH;
  const float* K = Kg + (size_t)b*NSP*CH;
  const float* V = Vg + (size_t)b*NSP*CH;
  for (int i = t; i < 1024; i += 256) {
    int r = i >> 5, c4 = (i & 31) << 2;
    *(float4*)&Qs[r][c4] = *(const float4*)&Q[(size_t)(n0 + r)*CH + c4];
  }
  if (t < 32) { mrow[t] = -1e30f; lrow[t] = 0.f; }
  float O[2][8];
  #pragma unroll
  for (int i = 0; i < 2; ++i)
    #pragma unroll
    for (int m = 0; m < 8; ++m) O[i][m] = 0.f;
  const float scale = 0.08838834764831845f;   // 1/sqrt(128)
  for (int kt = 0; kt < 128; ++kt) {
    __syncthreads();                          // prior PV done with Ks/Vs/Ss
    int kbase = kt << 5;
    for (int i = t; i < 1024; i += 256) {
      int r = i >> 5, c4 = (i & 31) << 2;
      *(float4*)&Ks[r][c4] = *(const float4*)&K[(size_t)(kbase + r)*CH + c4];
      *(float4*)&Vs[r][c4] = *(const float4*)&V[(size_t)(kbase + r)*CH + c4];
    }
    __syncthreads();
    float s00=0.f, s01=0.f, s10=0.f, s11=0.f;
    #pragma unroll 4
    for (int kk = 0; kk < 128; kk += 4) {
      float4 a0 = *(float4*)&Qs[ty     ][kk];
      float4 a1 = *(float4*)&Qs[ty + 16][kk];
      float4 b0 = *(float4*)&Ks[tx     ][kk];
      float4 b1 = *(float4*)&Ks[tx + 16][kk];
      s00 += a0.x*b0.x + a0.y*b0.y + a0.z*b0.z + a0.w*b0.w;
      s01 += a0.x*b1.x + a0.y*b1.y + a0.z*b1.z + a0.w*b1.w;
      s10 += a1.x*b0.x + a1.y*b0.y + a1.z*b0.z + a1.w*b0.w;
      s11 += a1.x*b1.x + a1.y*b1.y + a1.z*b1.z + a1.w*b1.w;
    }
    Ss[ty     ][tx     ] = s00*scale;
    Ss[ty     ][tx + 16] = s01*scale;
    Ss[ty + 16][tx     ] = s10*scale;
    Ss[ty + 16][tx + 16] = s11*scale;
    __syncthreads();
    if (t < 32) {
      float mold = mrow[t], mnew = mold;
      #pragma unroll
      for (int j = 0; j < 32; ++j) mnew = fmaxf(mnew, Ss[t][j]);
      float lsum = 0.f;
      #pragma unroll
      for (int j = 0; j < 32; ++j) {
        float p = __expf(Ss[t][j] - mnew); Ss[t][j] = p; lsum += p;
      }
      float alpha = __expf(mold - mnew);
      arow[t] = alpha; mrow[t] = mnew;
      lrow[t] = lrow[t]*alpha + lsum;
    }
    __syncthreads();
    float al0 = arow[ty], al1 = arow[ty+16];
    #pragma unroll
    for (int m = 0; m < 8; ++m) { O[0][m] *= al0; O[1][m] *= al1; }
    #pragma unroll 4
    for (int j = 0; j < 32; ++j) {
      float p0 = Ss[ty][j], p1 = Ss[ty+16][j];
      float4 v0 = *(float4*)&Vs[j][tx*8];
      float4 v1 = *(float4*)&Vs[j][tx*8 + 4];
      O[0][0]+=p0*v0.x; O[0][1]+=p0*v0.y; O[0][2]+=p0*v0.z; O[0][3]+=p0*v0.w;
      O[0][4]+=p0*v1.x; O[0][5]+=p0*v1.y; O[0][6]+=p0*v1.z; O[0][7]+=p0*v1.w;
      O[1][0]+=p1*v0.x; O[1][1]+=p1*v0.y; O[1][2]+=p1*v0.z; O[1][3]+=p1*v0.w;
      O[1][4]+=p1*v1.x; O[1][5]+=p1*v1.y; O[1][6]+=p1*v1.z; O[1][7]+=p1*v1.w;
    }
  }
  float inv0 = 1.f/lrow[ty], inv1 = 1.f/lrow[ty+16];
  float* p0 = Og + (size_t)(b*NSP + n0 + ty     )*CH + tx*8;
  float* p1 = Og + (size_t)(b*NSP + n0 + ty + 16)*CH + tx*8;
  *(float4*)&p0[0] = make_float4(O[0][0]*inv0, O[0][1]*inv0, O[0][2]*inv0, O[0][3]*inv0);
  *(float4*)&p0[4] = make_float4(O[0][4]*inv0, O[0][5]*inv0, O[0][6]*inv0, O[0][7]*inv0);
  *(float4*)&p1[0] = make_float4(O[1][0]*inv1, O[1][1]*inv1, O[1][2]*inv1, O[1][3]*inv1);
  *(float4*)&p1[4] = make_float4(O[1][4]*inv1, O[1][5]*inv1, O[1][6]*inv1, O[1][7]*inv1);
}

// ---------------- output = x + (w0*out_causal + w2*out_channel)^T ----------------
__global__ __launch_bounds__(256) void fuse_kernel(const float* __restrict__ x,
    const float* __restrict__ oc, const float* __restrict__ och,
    const float* __restrict__ wgt, float* __restrict__ out) {
  __shared__ float T[128][65];
  int t = threadIdx.x;
  int b  = blockIdx.x >> 6;
  int n0 = (blockIdx.x & 63) << 6;
  float w0 = wgt[b*3 + 0], w2 = wgt[b*3 + 2];
  const float* ocb  = oc  + (size_t)(b*NSP + n0)*CH;
  const float* ochb = och + (size_t)(b*NSP + n0)*CH;
  for (int i = t; i < 8192; i += 256) {           // coalesced over c
    int n = i >> 7, c = i & 127;
    T[c][n] = w0*ocb[(size_t)n*CH + c] + w2*ochb[(size_t)n*CH + c];
  }
  __syncthreads();
  for (int i = t; i < 8192; i += 256) {           // coalesced over n
    int c = i >> 6, n = i & 63;
    size_t idx = (size_t)(b*CH + c)*NSP + n0 + n;
    out[idx] = x[idx] + T[c][n];
  }
}

extern "C" void kernel_launch(void* const* d_in, const int* in_sizes, int n_in,
                              void* d_out, int out_size, void* d_ws, size_t ws_size,
                              hipStream_t stream) {
  (void)in_sizes; (void)n_in; (void)out_size; (void)ws_size;
  const float* x     = (const float*)d_in[0];
  const float* ln_g  = (const float*)d_in[1];
  const float* ln_b  = (const float*)d_in[2];
  const float* Wq    = (const float*)d_in[3];
  const float* bq    = (const float*)d_in[4];
  const float* Wk    = (const float*)d_in[5];
  const float* bk    = (const float*)d_in[6];
  const float* Wvc   = (const float*)d_in[7];
  const float* bvc   = (const float*)d_in[8];
  const float* Wvch  = (const float*)d_in[9];
  const float* bvch  = (const float*)d_in[10];
  const float* Wconv = (const float*)d_in[11];
  const float* bconv = (const float*)d_in[12];
  const float* Wg    = (const float*)d_in[13];
  const float* bg    = (const float*)d_in[14];

  float* out = (float*)d_out;
  float* cgf = out + (size_t)BIG;

  float* ws     = (float*)d_ws;
  float* xf     = ws;                         // later reused as out_causal
  float* q      = ws + 1*(size_t)BIG;
  float* k      = ws + 2*(size_t)BIG;
  float* vc     = ws + 3*(size_t)BIG;         // later reused as out_channel
  float* vch    = ws + 4*(size_t)BIG;
  float* Sch    = ws + 5*(size_t)BIG;         // (B,128,128)
  float* pooled = Sch + BATCH*CH*CH;          // (B,128)
  float* wgt    = pooled + BATCH*CH;          // (B,3)

  ln_kernel     <<<256, 256, 0, stream>>>(x, ln_g, ln_b, xf);
  pooled_kernel <<<512, 256, 0, stream>>>(x, pooled);
  gate_kernel   <<<1,   64,  0, stream>>>(pooled, Wg, bg, wgt);
  conv_kernel   <<<128, 256, 0, stream>>>(xf, Wconv, bconv, cgf);
  proj_kernel   <<<dim3(256,4), 256, 0, stream>>>(xf, Wq,bq, Wk,bk, Wvc,bvc, Wvch,bvch,
                                                  q, k, vc, vch);
  chscore_kernel<<<64,  256, 0, stream>>>(q, k, Sch);
  chsoftmax_kernel<<<512, 64, 0, stream>>>(Sch);
  flash_kernel  <<<512, 256, 0, stream>>>(q, k, vc, xf /*out_causal*/);
  chout_kernel  <<<256, 256, 0, stream>>>(vch, Sch, vc /*out_channel*/);
  fuse_kernel   <<<256, 256, 0, stream>>>(x, xf, vc, wgt, out);
}

// Round 2
// 850.472 us; speedup vs baseline: 1.6970x; 1.6970x over previous
//
#include <hip/hip_runtime.h>
#include <math.h>

#define CH   128
#define NSP  4096
#define BATCH 4
#define BIG  (BATCH*NSP*CH)   // 2,097,152 elements per (B,N,C) buffer

typedef short short8 __attribute__((ext_vector_type(8)));
typedef float floatx4 __attribute__((ext_vector_type(4)));

__device__ __forceinline__ unsigned short f2bu(float f) {
  union { float f; unsigned u; } v; v.f = f;
  unsigned r = v.u + 0x7fffu + ((v.u >> 16) & 1u);
  return (unsigned short)(r >> 16);
}
__device__ __forceinline__ float b2f(unsigned short h) {
  union { unsigned u; float f; } v; v.u = ((unsigned)h) << 16;
  return v.f;
}

// ---------------- LayerNorm over channels → xf (B*N, C) fp32 ----------------
__global__ __launch_bounds__(256) void ln_kernel(const float* __restrict__ x,
    const float* __restrict__ g, const float* __restrict__ bta, float* __restrict__ xf) {
  __shared__ float tile[128][65];
  __shared__ float pS[4][64];
  __shared__ float pQ[4][64];
  __shared__ float mu_s[64], rs_s[64];
  int t = threadIdx.x;
  int b  = blockIdx.x >> 6;
  int n0 = (blockIdx.x & 63) << 6;
  for (int i = t; i < 8192; i += 256) {
    int c = i >> 6, n = i & 63;
    tile[c][n] = x[(size_t)(b*CH + c)*NSP + n0 + n];
  }
  __syncthreads();
  {
    int n = t & 63, part = t >> 6;
    float s = 0.f, qq = 0.f;
    for (int c = part; c < 128; c += 4) { float v = tile[c][n]; s += v; qq += v*v; }
    pS[part][n] = s; pQ[part][n] = qq;
  }
  __syncthreads();
  if (t < 64) {
    float s = pS[0][t] + pS[1][t] + pS[2][t] + pS[3][t];
    float qq = pQ[0][t] + pQ[1][t] + pQ[2][t] + pQ[3][t];
    float mu = s * (1.f/128.f);
    float var = qq * (1.f/128.f) - mu*mu;
    mu_s[t] = mu;
    rs_s[t] = rsqrtf(var + 1e-5f);
  }
  __syncthreads();
  for (int i = t; i < 8192; i += 256) {
    int n = i >> 7, c = i & 127;
    float v = (tile[c][n] - mu_s[n]) * rs_s[n] * g[c] + bta[c];
    xf[(size_t)(b*NSP + n0 + n)*CH + c] = v;
  }
}

// ---------------- pooled = mean over spatial → (B,C) ----------------
__global__ __launch_bounds__(256) void pooled_kernel(const float* __restrict__ x,
                                                     float* __restrict__ pooled) {
  int bc = blockIdx.x; int t = threadIdx.x;
  const float4* p = (const float4*)(x + (size_t)bc*NSP);
  float s = 0.f;
  for (int i = t; i < 1024; i += 256) { float4 v = p[i]; s += v.x+v.y+v.z+v.w; }
  for (int off = 32; off; off >>= 1) s += __shfl_xor(s, off, 64);
  __shared__ float red[4];
  if ((t & 63) == 0) red[t >> 6] = s;
  __syncthreads();
  if (t == 0) pooled[bc] = (red[0]+red[1]+red[2]+red[3]) * (1.f/4096.f);
}

// ---------------- gate weights ----------------
__global__ void gate_kernel(const float* __restrict__ pooled, const float* __restrict__ Wg,
                            const float* __restrict__ bg, float* __restrict__ wgt) {
  __shared__ float lg[4][3];
  int t = threadIdx.x;
  if (t < 12) {
    int b = t / 3, j = t % 3;
    float s = bg[j];
    const float* pr = pooled + b*CH;
    const float* wr = Wg + j*CH;
    for (int c = 0; c < CH; ++c) s += pr[c]*wr[c];
    lg[b][j] = s;
  }
  __syncthreads();
  if (t < 4) {
    float a = lg[t][0], b2 = lg[t][1], c = lg[t][2];
    float m = fmaxf(a, fmaxf(b2, c));
    float e0 = __expf(a-m), e1 = __expf(b2-m), e2 = __expf(c-m);
    float inv = 1.f/(e0+e1+e2);
    wgt[t*3+0] = e0*inv; wgt[t*3+1] = e1*inv; wgt[t*3+2] = e2*inv;
  }
}

// ---------------- Conv3d C->2, k=3, SAME ----------------
__global__ __launch_bounds__(256) void conv_kernel(const float* __restrict__ xf,
    const float* __restrict__ Wc, const float* __restrict__ bc_, float* __restrict__ cgf) {
  int gid = blockIdx.x*256 + threadIdx.x;
  int sp = gid & 4095;
  int o  = (gid >> 12) & 1;
  int b  = gid >> 13;
  int z = sp >> 8, y = (sp >> 4) & 15, xw = sp & 15;
  float acc = bc_[o];
  const float* Wo = Wc + o*3456;
  for (int kd = 0; kd < 3; ++kd) {
    int zz = z + kd - 1; if ((unsigned)zz >= 16u) continue;
    for (int kh = 0; kh < 3; ++kh) {
      int yy = y + kh - 1; if ((unsigned)yy >= 16u) continue;
      for (int kw = 0; kw < 3; ++kw) {
        int xx = xw + kw - 1; if ((unsigned)xx >= 16u) continue;
        int n = (zz << 8) + (yy << 4) + xx;
        const float4* xr = (const float4*)(xf + (size_t)(b*NSP + n)*CH);
        const float* wt = Wo + kd*9 + kh*3 + kw;
        #pragma unroll 8
        for (int c4 = 0; c4 < 32; ++c4) {
          float4 xv = xr[c4];
          int cb = c4*4;
          acc += xv.x*wt[cb*27] + xv.y*wt[(cb+1)*27]
               + xv.z*wt[(cb+2)*27] + xv.w*wt[(cb+3)*27];
        }
      }
    }
  }
  cgf[gid] = acc;
}

// ---------------- 64x128 GEMM tile (fp32 out) ----------------
__device__ __forceinline__ void gemm_tile_64x128(const float* __restrict__ X, int R0,
    const float* __restrict__ W, const float* __restrict__ bias, float* __restrict__ Y) {
  __shared__ float Xs[64][132];
  int t = threadIdx.x; int tx = t & 15; int ty = t >> 4;
  for (int i = t; i < 2048; i += 256) {
    int r = i >> 5, c4 = (i & 31) << 2;
    *(float4*)&Xs[r][c4] = *(const float4*)&X[(size_t)(R0 + r)*CH + c4];
  }
  __syncthreads();
  float acc[4][8];
  #pragma unroll
  for (int i = 0; i < 4; ++i)
    #pragma unroll
    for (int m = 0; m < 8; ++m) acc[i][m] = 0.f;
  int o0 = tx*8;
  #pragma unroll 2
  for (int k4 = 0; k4 < 128; k4 += 4) {
    float4 a0 = *(float4*)&Xs[ty     ][k4];
    float4 a1 = *(float4*)&Xs[ty + 16][k4];
    float4 a2 = *(float4*)&Xs[ty + 32][k4];
    float4 a3 = *(float4*)&Xs[ty + 48][k4];
    #pragma unroll
    for (int m = 0; m < 8; ++m) {
      float4 w = *(const float4*)&W[(size_t)(o0+m)*CH + k4];
      acc[0][m] += a0.x*w.x + a0.y*w.y + a0.z*w.z + a0.w*w.w;
      acc[1][m] += a1.x*w.x + a1.y*w.y + a1.z*w.z + a1.w*w.w;
      acc[2][m] += a2.x*w.x + a2.y*w.y + a2.z*w.z + a2.w*w.w;
      acc[3][m] += a3.x*w.x + a3.y*w.y + a3.z*w.z + a3.w*w.w;
    }
  }
  float bs[8];
  #pragma unroll
  for (int m = 0; m < 8; ++m) bs[m] = bias ? bias[o0+m] : 0.f;
  #pragma unroll
  for (int i = 0; i < 4; ++i) {
    size_t r = (size_t)(R0 + ty + 16*i);
    float4 v0 = make_float4(acc[i][0]+bs[0], acc[i][1]+bs[1], acc[i][2]+bs[2], acc[i][3]+bs[3]);
    float4 v1 = make_float4(acc[i][4]+bs[4], acc[i][5]+bs[5], acc[i][6]+bs[6], acc[i][7]+bs[7]);
    *(float4*)&Y[r*CH + o0    ] = v0;
    *(float4*)&Y[r*CH + o0 + 4] = v1;
  }
}

// ---------------- 64x128 GEMM tile (bf16 out) ----------------
__device__ __forceinline__ void gemm_tile_64x128_b16(const float* __restrict__ X, int R0,
    const float* __restrict__ W, const float* __restrict__ bias, unsigned short* __restrict__ Y) {
  __shared__ float Xs[64][132];
  int t = threadIdx.x; int tx = t & 15; int ty = t >> 4;
  for (int i = t; i < 2048; i += 256) {
    int r = i >> 5, c4 = (i & 31) << 2;
    *(float4*)&Xs[r][c4] = *(const float4*)&X[(size_t)(R0 + r)*CH + c4];
  }
  __syncthreads();
  float acc[4][8];
  #pragma unroll
  for (int i = 0; i < 4; ++i)
    #pragma unroll
    for (int m = 0; m < 8; ++m) acc[i][m] = 0.f;
  int o0 = tx*8;
  #pragma unroll 2
  for (int k4 = 0; k4 < 128; k4 += 4) {
    float4 a0 = *(float4*)&Xs[ty     ][k4];
    float4 a1 = *(float4*)&Xs[ty + 16][k4];
    float4 a2 = *(float4*)&Xs[ty + 32][k4];
    float4 a3 = *(float4*)&Xs[ty + 48][k4];
    #pragma unroll
    for (int m = 0; m < 8; ++m) {
      float4 w = *(const float4*)&W[(size_t)(o0+m)*CH + k4];
      acc[0][m] += a0.x*w.x + a0.y*w.y + a0.z*w.z + a0.w*w.w;
      acc[1][m] += a1.x*w.x + a1.y*w.y + a1.z*w.z + a1.w*w.w;
      acc[2][m] += a2.x*w.x + a2.y*w.y + a2.z*w.z + a2.w*w.w;
      acc[3][m] += a3.x*w.x + a3.y*w.y + a3.z*w.z + a3.w*w.w;
    }
  }
  float bs[8];
  #pragma unroll
  for (int m = 0; m < 8; ++m) bs[m] = bias[o0+m];
  #pragma unroll
  for (int i = 0; i < 4; ++i) {
    size_t r = (size_t)(R0 + ty + 16*i);
    short8 pk;
    #pragma unroll
    for (int m = 0; m < 8; ++m) pk[m] = (short)f2bu(acc[i][m] + bs[m]);
    *(short8*)&Y[r*CH + o0] = pk;
  }
}

__global__ __launch_bounds__(256) void proj_kernel(const float* __restrict__ xf,
    const float* __restrict__ Wq, const float* __restrict__ bq,
    const float* __restrict__ Wk, const float* __restrict__ bk,
    const float* __restrict__ Wvc, const float* __restrict__ bvc,
    const float* __restrict__ Wvch, const float* __restrict__ bvch,
    unsigned short* __restrict__ q, unsigned short* __restrict__ k,
    unsigned short* __restrict__ vc, float* __restrict__ vch) {
  int R0 = blockIdx.x * 64;
  if (blockIdx.y == 0)      gemm_tile_64x128_b16(xf, R0, Wq,  bq,  q);
  else if (blockIdx.y == 1) gemm_tile_64x128_b16(xf, R0, Wk,  bk,  k);
  else if (blockIdx.y == 2) gemm_tile_64x128_b16(xf, R0, Wvc, bvc, vc);
  else                      gemm_tile_64x128(xf, R0, Wvch, bvch, vch);
}

// out_channel[n][c] = sum_d vch[n][d] * A[c][d]; in-place over vch (row-exclusive per block)
__global__ __launch_bounds__(256) void chout_kernel(float* __restrict__ vch,
    const float* __restrict__ A) {
  int R0 = blockIdx.x * 64;
  int b = blockIdx.x >> 6;
  gemm_tile_64x128(vch, R0, A + (size_t)b*CH*CH, nullptr, vch);
}

// ---------------- channel scores S[b][c][d] = sum_n q[n][c]k[n][d] (bf16 in) ----------------
__global__ __launch_bounds__(256) void chscore_kernel(const unsigned short* __restrict__ q,
    const unsigned short* __restrict__ k, float* __restrict__ S) {
  int b = blockIdx.x >> 4, ct = blockIdx.x & 15;
  int t = threadIdx.x;
  int d = t & 127, cg = t >> 7;
  int cb = ct*8 + cg*4;
  const unsigned short* qb = q + (size_t)b*NSP*CH;
  const unsigned short* kb = k + (size_t)b*NSP*CH;
  float a0=0.f, a1=0.f, a2=0.f, a3=0.f;
  for (int n = 0; n < NSP; ++n) {
    float kv = b2f(kb[(size_t)n*CH + d]);
    const unsigned short* q0 = qb + (size_t)n*CH + cb;
    a0 += b2f(q0[0])*kv;
    a1 += b2f(q0[1])*kv;
    a2 += b2f(q0[2])*kv;
    a3 += b2f(q0[3])*kv;
  }
  float* Sr = S + ((size_t)b*CH + cb)*CH + d;
  Sr[0]    = a0;
  Sr[CH]   = a1;
  Sr[2*CH] = a2;
  Sr[3*CH] = a3;
}

__global__ __launch_bounds__(64) void chsoftmax_kernel(float* __restrict__ S) {
  int row = blockIdx.x; int t = threadIdx.x;
  float* r = S + (size_t)row*CH;
  const float sc = 1.f/64.f;
  float s0 = r[t]*sc, s1 = r[t+64]*sc;
  float m = fmaxf(s0, s1);
  for (int off = 32; off; off >>= 1) m = fmaxf(m, __shfl_xor(m, off, 64));
  float p0 = __expf(s0 - m), p1 = __expf(s1 - m);
  float s = p0 + p1;
  for (int off = 32; off; off >>= 1) s += __shfl_xor(s, off, 64);
  float inv = 1.f/s;
  r[t]    = p0*inv;
  r[t+64] = p1*inv;
}

// ---------------- MFMA flash attention: 64 Q rows/block, 4 waves x 16 rows ----------------
// mfma_f32_16x16x32_bf16 layouts (learn_hip verified):
//   A[m=lane&15][k=quad*8+j]; B[k=quad*8+j][n=lane&15]; C/D: col=lane&15, row=quad*4+reg.
__global__ __launch_bounds__(256) void flash_mfma_kernel(
    const unsigned short* __restrict__ Qg, const unsigned short* __restrict__ Kg,
    const unsigned short* __restrict__ Vg, float* __restrict__ Og) {
  __shared__ unsigned short Ks[64][136];   // K-tile row-major, rows 16B-aligned (272B)
  __shared__ unsigned short Vt[128][72];   // V-tile transposed [c][n], rows 144B
  __shared__ unsigned short Ps[4][16][72]; // per-wave P scratch (C-layout -> A-layout)

  int t = threadIdx.x;
  int lane = t & 63;
  int w = t >> 6;
  int id = lane & 15;
  int quad = lane >> 4;

  int b  = blockIdx.x >> 6;
  int n0 = (blockIdx.x & 63) << 6;

  const unsigned short* Qb = Qg + (size_t)b*NSP*CH;
  const unsigned short* Kb = Kg + (size_t)b*NSP*CH;
  const unsigned short* Vb = Vg + (size_t)b*NSP*CH;

  // Q fragments for this wave's 16 rows, 4 k-chunks of 32 channels
  short8 qf[4];
  {
    const unsigned short* qp = Qb + (size_t)(n0 + w*16 + id)*CH + quad*8;
    #pragma unroll
    for (int kc = 0; kc < 4; ++kc) qf[kc] = *(const short8*)(qp + kc*32);
  }

  float mrun[4], lrun[4];
  #pragma unroll
  for (int r = 0; r < 4; ++r) { mrun[r] = -1e30f; lrun[r] = 0.f; }
  floatx4 Oacc[8];
  #pragma unroll
  for (int ct = 0; ct < 8; ++ct) Oacc[ct] = (floatx4){0.f,0.f,0.f,0.f};

  const float scale = 0.08838834764831845f;  // 1/sqrt(128)

  for (int kt = 0; kt < 64; ++kt) {
    int kbase = kt << 6;
    __syncthreads();   // previous iteration done with Ks/Vt
    // stage K: 64 rows x 128 ch, 1024 chunks of 8 bf16, coalesced
    for (int i = t; i < 1024; i += 256) {
      int r = i >> 4, c8 = (i & 15) << 3;
      *(short8*)&Ks[r][c8] = *(const short8*)(Kb + (size_t)(kbase + r)*CH + c8);
    }
    // stage V transposed: thread reads 8 rows of one column, writes one b128 row chunk
    #pragma unroll
    for (int it = 0; it < 4; ++it) {
      int task = t + it*256;            // 0..1023
      int c = task & 127, r0 = (task >> 7) << 3;
      short8 vv;
      #pragma unroll
      for (int j = 0; j < 8; ++j)
        vv[j] = (short)Vb[(size_t)(kbase + r0 + j)*CH + c];
      *(short8*)&Vt[c][r0] = vv;
    }
    __syncthreads();

    // S = Q K^T for this wave's 16 rows x 64 K-cols
    floatx4 S[4];
    #pragma unroll
    for (int nt = 0; nt < 4; ++nt) {
      floatx4 acc = (floatx4){0.f,0.f,0.f,0.f};
      #pragma unroll
      for (int kc = 0; kc < 4; ++kc) {
        short8 kf = *(const short8*)&Ks[nt*16 + id][kc*32 + quad*8];
        acc = __builtin_amdgcn_mfma_f32_16x16x32_bf16(qf[kc], kf, acc, 0, 0, 0);
      }
      S[nt] = acc;
    }

    // online softmax in C-layout: lane handles rows quad*4+r, cols id+nt*16
    float sv[4][4], m4[4];
    #pragma unroll
    for (int r = 0; r < 4; ++r) {
      #pragma unroll
      for (int nt = 0; nt < 4; ++nt) sv[nt][r] = S[nt][r] * scale;
      m4[r] = fmaxf(fmaxf(sv[0][r], sv[1][r]), fmaxf(sv[2][r], sv[3][r]));
    }
    #pragma unroll
    for (int off = 1; off <= 8; off <<= 1)
      #pragma unroll
      for (int r = 0; r < 4; ++r) m4[r] = fmaxf(m4[r], __shfl_xor(m4[r], off, 64));
    float alpha[4];
    #pragma unroll
    for (int r = 0; r < 4; ++r) {
      float mn = fmaxf(mrun[r], m4[r]);
      alpha[r] = __expf(mrun[r] - mn);
      mrun[r] = mn;
    }
    float rs[4] = {0.f,0.f,0.f,0.f};
    float pv[4][4];
    #pragma unroll
    for (int nt = 0; nt < 4; ++nt)
      #pragma unroll
      for (int r = 0; r < 4; ++r) {
        float p = __expf(sv[nt][r] - mrun[r]);
        pv[nt][r] = p; rs[r] += p;
      }
    #pragma unroll
    for (int off = 1; off <= 8; off <<= 1)
      #pragma unroll
      for (int r = 0; r < 4; ++r) rs[r] += __shfl_xor(rs[r], off, 64);
    #pragma unroll
    for (int r = 0; r < 4; ++r) lrun[r] = lrun[r]*alpha[r] + rs[r];

    // P -> LDS (C-layout write), reread in A-layout
    #pragma unroll
    for (int nt = 0; nt < 4; ++nt)
      #pragma unroll
      for (int r = 0; r < 4; ++r)
        Ps[w][quad*4 + r][nt*16 + id] = f2bu(pv[nt][r]);

    // rescale O
    #pragma unroll
    for (int ct = 0; ct < 8; ++ct)
      #pragma unroll
      for (int r = 0; r < 4; ++r) Oacc[ct][r] *= alpha[r];

    // O += P V
    #pragma unroll
    for (int nc = 0; nc < 2; ++nc) {
      short8 pf = *(const short8*)&Ps[w][id][nc*32 + quad*8];
      #pragma unroll
      for (int ct = 0; ct < 8; ++ct) {
        short8 vf = *(const short8*)&Vt[ct*16 + id][nc*32 + quad*8];
        Oacc[ct] = __builtin_amdgcn_mfma_f32_16x16x32_bf16(pf, vf, Oacc[ct], 0, 0, 0);
      }
    }
  }

  // epilogue: normalize and store fp32
  float inv[4];
  #pragma unroll
  for (int r = 0; r < 4; ++r) inv[r] = 1.f / lrun[r];
  #pragma unroll
  for (int ct = 0; ct < 8; ++ct)
    #pragma unroll
    for (int r = 0; r < 4; ++r) {
      int row = n0 + w*16 + quad*4 + r;
      Og[(size_t)(b*NSP + row)*CH + ct*16 + id] = Oacc[ct][r] * inv[r];
    }
}

// ---------------- output = x + (w0*out_causal + w2*out_channel)^T ----------------
__global__ __launch_bounds__(256) void fuse_kernel(const float* __restrict__ x,
    const float* __restrict__ oc, const float* __restrict__ och,
    const float* __restrict__ wgt, float* __restrict__ out) {
  __shared__ float T[128][65];
  int t = threadIdx.x;
  int b  = blockIdx.x >> 6;
  int n0 = (blockIdx.x & 63) << 6;
  float w0 = wgt[b*3 + 0], w2 = wgt[b*3 + 2];
  const float* ocb  = oc  + (size_t)(b*NSP + n0)*CH;
  const float* ochb = och + (size_t)(b*NSP + n0)*CH;
  for (int i = t; i < 8192; i += 256) {
    int n = i >> 7, c = i & 127;
    T[c][n] = w0*ocb[(size_t)n*CH + c] + w2*ochb[(size_t)n*CH + c];
  }
  __syncthreads();
  for (int i = t; i < 8192; i += 256) {
    int c = i >> 6, n = i & 63;
    size_t idx = (size_t)(b*CH + c)*NSP + n0 + n;
    out[idx] = x[idx] + T[c][n];
  }
}

extern "C" void kernel_launch(void* const* d_in, const int* in_sizes, int n_in,
                              void* d_out, int out_size, void* d_ws, size_t ws_size,
                              hipStream_t stream) {
  (void)in_sizes; (void)n_in; (void)out_size; (void)ws_size;
  const float* x     = (const float*)d_in[0];
  const float* ln_g  = (const float*)d_in[1];
  const float* ln_b  = (const float*)d_in[2];
  const float* Wq    = (const float*)d_in[3];
  const float* bq    = (const float*)d_in[4];
  const float* Wk    = (const float*)d_in[5];
  const float* bk    = (const float*)d_in[6];
  const float* Wvc   = (const float*)d_in[7];
  const float* bvc   = (const float*)d_in[8];
  const float* Wvch  = (const float*)d_in[9];
  const float* bvch  = (const float*)d_in[10];
  const float* Wconv = (const float*)d_in[11];
  const float* bconv = (const float*)d_in[12];
  const float* Wg    = (const float*)d_in[13];
  const float* bg    = (const float*)d_in[14];

  float* out = (float*)d_out;
  float* cgf = out + (size_t)BIG;

  float* ws   = (float*)d_ws;
  float* xf   = ws;                        // fp32; reused as out_causal
  float* vch  = ws + (size_t)BIG;          // fp32; reused in-place as out_channel
  float* Sch  = ws + 2*(size_t)BIG;        // (B,128,128) fp32
  float* pooled = Sch + BATCH*CH*CH;       // (B,128)
  float* wgt    = pooled + BATCH*CH;       // (B,3)
  unsigned short* qb  = (unsigned short*)(wgt + 16);  // bf16 buffers (16B-aligned)
  unsigned short* kb  = qb + (size_t)BIG;
  unsigned short* vcb = kb + (size_t)BIG;

  ln_kernel     <<<256, 256, 0, stream>>>(x, ln_g, ln_b, xf);
  pooled_kernel <<<512, 256, 0, stream>>>(x, pooled);
  gate_kernel   <<<1,   64,  0, stream>>>(pooled, Wg, bg, wgt);
  conv_kernel   <<<128, 256, 0, stream>>>(xf, Wconv, bconv, cgf);
  proj_kernel   <<<dim3(256,4), 256, 0, stream>>>(xf, Wq,bq, Wk,bk, Wvc,bvc, Wvch,bvch,
                                                  qb, kb, vcb, vch);
  chscore_kernel<<<64,  256, 0, stream>>>(qb, kb, Sch);
  chsoftmax_kernel<<<512, 64, 0, stream>>>(Sch);
  flash_mfma_kernel<<<256, 256, 0, stream>>>(qb, kb, vcb, xf /*out_causal*/);
  chout_kernel  <<<256, 256, 0, stream>>>(vch, Sch);
  fuse_kernel   <<<256, 256, 0, stream>>>(x, xf, vch, wgt, out);
}

// Round 3
// 575.599 us; speedup vs baseline: 2.5074x; 1.4775x over previous
//
#include <hip/hip_runtime.h>
#include <math.h>

#define CH   128
#define NSP  4096
#define BATCH 4
#define BIG  (BATCH*NSP*CH)   // 2,097,152 elements per (B,N,C) buffer
#define KCHUNKS 16            // split-K chunks for chscore (256 n-rows each)

typedef short short8 __attribute__((ext_vector_type(8)));
typedef float floatx4 __attribute__((ext_vector_type(4)));

__device__ __forceinline__ unsigned short f2bu(float f) {
  union { float f; unsigned u; } v; v.f = f;
  unsigned r = v.u + 0x7fffu + ((v.u >> 16) & 1u);
  return (unsigned short)(r >> 16);
}
__device__ __forceinline__ float b2f(unsigned short h) {
  union { unsigned u; float f; } v; v.u = ((unsigned)h) << 16;
  return v.f;
}

// ---------------- LayerNorm over channels → xf (B*N, C) fp32 ----------------
__global__ __launch_bounds__(256) void ln_kernel(const float* __restrict__ x,
    const float* __restrict__ g, const float* __restrict__ bta, float* __restrict__ xf) {
  __shared__ float tile[128][65];
  __shared__ float pS[4][64];
  __shared__ float pQ[4][64];
  __shared__ float mu_s[64], rs_s[64];
  int t = threadIdx.x;
  int b  = blockIdx.x >> 6;
  int n0 = (blockIdx.x & 63) << 6;
  for (int i = t; i < 8192; i += 256) {
    int c = i >> 6, n = i & 63;
    tile[c][n] = x[(size_t)(b*CH + c)*NSP + n0 + n];
  }
  __syncthreads();
  {
    int n = t & 63, part = t >> 6;
    float s = 0.f, qq = 0.f;
    for (int c = part; c < 128; c += 4) { float v = tile[c][n]; s += v; qq += v*v; }
    pS[part][n] = s; pQ[part][n] = qq;
  }
  __syncthreads();
  if (t < 64) {
    float s = pS[0][t] + pS[1][t] + pS[2][t] + pS[3][t];
    float qq = pQ[0][t] + pQ[1][t] + pQ[2][t] + pQ[3][t];
    float mu = s * (1.f/128.f);
    float var = qq * (1.f/128.f) - mu*mu;
    mu_s[t] = mu;
    rs_s[t] = rsqrtf(var + 1e-5f);
  }
  __syncthreads();
  for (int i = t; i < 8192; i += 256) {
    int n = i >> 7, c = i & 127;
    float v = (tile[c][n] - mu_s[n]) * rs_s[n] * g[c] + bta[c];
    xf[(size_t)(b*NSP + n0 + n)*CH + c] = v;
  }
}

// ---------------- pooled = mean over spatial → (B,C) ----------------
__global__ __launch_bounds__(256) void pooled_kernel(const float* __restrict__ x,
                                                     float* __restrict__ pooled) {
  int bc = blockIdx.x; int t = threadIdx.x;
  const float4* p = (const float4*)(x + (size_t)bc*NSP);
  float s = 0.f;
  for (int i = t; i < 1024; i += 256) { float4 v = p[i]; s += v.x+v.y+v.z+v.w; }
  for (int off = 32; off; off >>= 1) s += __shfl_xor(s, off, 64);
  __shared__ float red[4];
  if ((t & 63) == 0) red[t >> 6] = s;
  __syncthreads();
  if (t == 0) pooled[bc] = (red[0]+red[1]+red[2]+red[3]) * (1.f/4096.f);
}

// ---------------- gate weights ----------------
__global__ void gate_kernel(const float* __restrict__ pooled, const float* __restrict__ Wg,
                            const float* __restrict__ bg, float* __restrict__ wgt) {
  __shared__ float lg[4][3];
  int t = threadIdx.x;
  if (t < 12) {
    int b = t / 3, j = t % 3;
    float s = bg[j];
    const float* pr = pooled + b*CH;
    const float* wr = Wg + j*CH;
    for (int c = 0; c < CH; ++c) s += pr[c]*wr[c];
    lg[b][j] = s;
  }
  __syncthreads();
  if (t < 4) {
    float a = lg[t][0], b2 = lg[t][1], c = lg[t][2];
    float m = fmaxf(a, fmaxf(b2, c));
    float e0 = __expf(a-m), e1 = __expf(b2-m), e2 = __expf(c-m);
    float inv = 1.f/(e0+e1+e2);
    wgt[t*3+0] = e0*inv; wgt[t*3+1] = e1*inv; wgt[t*3+2] = e2*inv;
  }
}

// ---------------- Conv3d C->2, k=3, SAME ----------------
__global__ __launch_bounds__(256) void conv_kernel(const float* __restrict__ xf,
    const float* __restrict__ Wc, const float* __restrict__ bc_, float* __restrict__ cgf) {
  int gid = blockIdx.x*256 + threadIdx.x;
  int sp = gid & 4095;
  int o  = (gid >> 12) & 1;
  int b  = gid >> 13;
  int z = sp >> 8, y = (sp >> 4) & 15, xw = sp & 15;
  float acc = bc_[o];
  const float* Wo = Wc + o*3456;
  for (int kd = 0; kd < 3; ++kd) {
    int zz = z + kd - 1; if ((unsigned)zz >= 16u) continue;
    for (int kh = 0; kh < 3; ++kh) {
      int yy = y + kh - 1; if ((unsigned)yy >= 16u) continue;
      for (int kw = 0; kw < 3; ++kw) {
        int xx = xw + kw - 1; if ((unsigned)xx >= 16u) continue;
        int n = (zz << 8) + (yy << 4) + xx;
        const float4* xr = (const float4*)(xf + (size_t)(b*NSP + n)*CH);
        const float* wt = Wo + kd*9 + kh*3 + kw;
        #pragma unroll 8
        for (int c4 = 0; c4 < 32; ++c4) {
          float4 xv = xr[c4];
          int cb = c4*4;
          acc += xv.x*wt[cb*27] + xv.y*wt[(cb+1)*27]
               + xv.z*wt[(cb+2)*27] + xv.w*wt[(cb+3)*27];
        }
      }
    }
  }
  cgf[gid] = acc;
}

// ---------------- 64x128 GEMM tile (fp32 out) ----------------
__device__ __forceinline__ void gemm_tile_64x128(const float* __restrict__ X, int R0,
    const float* __restrict__ W, const float* __restrict__ bias, float* __restrict__ Y) {
  __shared__ float Xs[64][132];
  int t = threadIdx.x; int tx = t & 15; int ty = t >> 4;
  for (int i = t; i < 2048; i += 256) {
    int r = i >> 5, c4 = (i & 31) << 2;
    *(float4*)&Xs[r][c4] = *(const float4*)&X[(size_t)(R0 + r)*CH + c4];
  }
  __syncthreads();
  float acc[4][8];
  #pragma unroll
  for (int i = 0; i < 4; ++i)
    #pragma unroll
    for (int m = 0; m < 8; ++m) acc[i][m] = 0.f;
  int o0 = tx*8;
  #pragma unroll 2
  for (int k4 = 0; k4 < 128; k4 += 4) {
    float4 a0 = *(float4*)&Xs[ty     ][k4];
    float4 a1 = *(float4*)&Xs[ty + 16][k4];
    float4 a2 = *(float4*)&Xs[ty + 32][k4];
    float4 a3 = *(float4*)&Xs[ty + 48][k4];
    #pragma unroll
    for (int m = 0; m < 8; ++m) {
      float4 w = *(const float4*)&W[(size_t)(o0+m)*CH + k4];
      acc[0][m] += a0.x*w.x + a0.y*w.y + a0.z*w.z + a0.w*w.w;
      acc[1][m] += a1.x*w.x + a1.y*w.y + a1.z*w.z + a1.w*w.w;
      acc[2][m] += a2.x*w.x + a2.y*w.y + a2.z*w.z + a2.w*w.w;
      acc[3][m] += a3.x*w.x + a3.y*w.y + a3.z*w.z + a3.w*w.w;
    }
  }
  float bs[8];
  #pragma unroll
  for (int m = 0; m < 8; ++m) bs[m] = bias ? bias[o0+m] : 0.f;
  #pragma unroll
  for (int i = 0; i < 4; ++i) {
    size_t r = (size_t)(R0 + ty + 16*i);
    float4 v0 = make_float4(acc[i][0]+bs[0], acc[i][1]+bs[1], acc[i][2]+bs[2], acc[i][3]+bs[3]);
    float4 v1 = make_float4(acc[i][4]+bs[4], acc[i][5]+bs[5], acc[i][6]+bs[6], acc[i][7]+bs[7]);
    *(float4*)&Y[r*CH + o0    ] = v0;
    *(float4*)&Y[r*CH + o0 + 4] = v1;
  }
}

// ---------------- 64x128 GEMM tile (bf16 out) ----------------
__device__ __forceinline__ void gemm_tile_64x128_b16(const float* __restrict__ X, int R0,
    const float* __restrict__ W, const float* __restrict__ bias, unsigned short* __restrict__ Y) {
  __shared__ float Xs[64][132];
  int t = threadIdx.x; int tx = t & 15; int ty = t >> 4;
  for (int i = t; i < 2048; i += 256) {
    int r = i >> 5, c4 = (i & 31) << 2;
    *(float4*)&Xs[r][c4] = *(const float4*)&X[(size_t)(R0 + r)*CH + c4];
  }
  __syncthreads();
  float acc[4][8];
  #pragma unroll
  for (int i = 0; i < 4; ++i)
    #pragma unroll
    for (int m = 0; m < 8; ++m) acc[i][m] = 0.f;
  int o0 = tx*8;
  #pragma unroll 2
  for (int k4 = 0; k4 < 128; k4 += 4) {
    float4 a0 = *(float4*)&Xs[ty     ][k4];
    float4 a1 = *(float4*)&Xs[ty + 16][k4];
    float4 a2 = *(float4*)&Xs[ty + 32][k4];
    float4 a3 = *(float4*)&Xs[ty + 48][k4];
    #pragma unroll
    for (int m = 0; m < 8; ++m) {
      float4 w = *(const float4*)&W[(size_t)(o0+m)*CH + k4];
      acc[0][m] += a0.x*w.x + a0.y*w.y + a0.z*w.z + a0.w*w.w;
      acc[1][m] += a1.x*w.x + a1.y*w.y + a1.z*w.z + a1.w*w.w;
      acc[2][m] += a2.x*w.x + a2.y*w.y + a2.z*w.z + a2.w*w.w;
      acc[3][m] += a3.x*w.x + a3.y*w.y + a3.z*w.z + a3.w*w.w;
    }
  }
  float bs[8];
  #pragma unroll
  for (int m = 0; m < 8; ++m) bs[m] = bias[o0+m];
  #pragma unroll
  for (int i = 0; i < 4; ++i) {
    size_t r = (size_t)(R0 + ty + 16*i);
    short8 pk;
    #pragma unroll
    for (int m = 0; m < 8; ++m) pk[m] = (short)f2bu(acc[i][m] + bs[m]);
    *(short8*)&Y[r*CH + o0] = pk;
  }
}

__global__ __launch_bounds__(256) void proj_kernel(const float* __restrict__ xf,
    const float* __restrict__ Wq, const float* __restrict__ bq,
    const float* __restrict__ Wk, const float* __restrict__ bk,
    const float* __restrict__ Wvc, const float* __restrict__ bvc,
    const float* __restrict__ Wvch, const float* __restrict__ bvch,
    unsigned short* __restrict__ q, unsigned short* __restrict__ k,
    unsigned short* __restrict__ vc, float* __restrict__ vch) {
  int R0 = blockIdx.x * 64;
  if (blockIdx.y == 0)      gemm_tile_64x128_b16(xf, R0, Wq,  bq,  q);
  else if (blockIdx.y == 1) gemm_tile_64x128_b16(xf, R0, Wk,  bk,  k);
  else if (blockIdx.y == 2) gemm_tile_64x128_b16(xf, R0, Wvc, bvc, vc);
  else                      gemm_tile_64x128(xf, R0, Wvch, bvch, vch);
}

// out_channel[n][c] = sum_d vch[n][d] * A[c][d]; in-place over vch (row-exclusive per block)
__global__ __launch_bounds__(256) void chout_kernel(float* __restrict__ vch,
    const float* __restrict__ A) {
  int R0 = blockIdx.x * 64;
  int b = blockIdx.x >> 6;
  gemm_tile_64x128(vch, R0, A + (size_t)b*CH*CH, nullptr, vch);
}

// ---------------- channel scores: split-K MFMA. Sp[p][b][c][d] partials ----------------
// S[b][c][d] = sum_n q[b][n][c] * k[b][n][d]  (GEMM: M=c, N=d, K=n)
// A[m=c][k=n] needs q transposed; B[k=n][n=d] needs k transposed for b128 frags.
__global__ __launch_bounds__(256) void chscore_kernel(const unsigned short* __restrict__ q,
    const unsigned short* __restrict__ k, float* __restrict__ Sp) {
  __shared__ unsigned short Qt[128][72];   // [c][n], 64-n stage
  __shared__ unsigned short Kt[128][72];   // [d][n]
  int t = threadIdx.x;
  int lane = t & 63, w = t >> 6;
  int id = lane & 15, quad = lane >> 4;
  int p = blockIdx.x;                      // split-K chunk (256 n-rows)
  int b = blockIdx.y;
  const unsigned short* qb = q + (size_t)b*NSP*CH;
  const unsigned short* kb = k + (size_t)b*NSP*CH;

  floatx4 acc[2][8];
  #pragma unroll
  for (int mt = 0; mt < 2; ++mt)
    #pragma unroll
    for (int nt = 0; nt < 8; ++nt) acc[mt][nt] = (floatx4){0.f,0.f,0.f,0.f};

  for (int s = 0; s < 4; ++s) {
    int nbase = p*256 + s*64;
    __syncthreads();
    // transpose-stage 64 n-rows of q and k: coalesced 2B global reads, b128 LDS writes
    #pragma unroll
    for (int it = 0; it < 4; ++it) {
      int task = t + it*256;               // 0..1023
      int c = task & 127, r0 = (task >> 7) << 3;
      short8 vq, vk;
      #pragma unroll
      for (int j = 0; j < 8; ++j) {
        size_t off = (size_t)(nbase + r0 + j)*CH + c;
        vq[j] = (short)qb[off];
        vk[j] = (short)kb[off];
      }
      *(short8*)&Qt[c][r0] = vq;
      *(short8*)&Kt[c][r0] = vk;
    }
    __syncthreads();
    #pragma unroll
    for (int kc = 0; kc < 2; ++kc) {
      short8 af0 = *(const short8*)&Qt[w*32 + id     ][kc*32 + quad*8];
      short8 af1 = *(const short8*)&Qt[w*32 + 16 + id][kc*32 + quad*8];
      #pragma unroll
      for (int nt = 0; nt < 8; ++nt) {
        short8 bf = *(const short8*)&Kt[nt*16 + id][kc*32 + quad*8];
        acc[0][nt] = __builtin_amdgcn_mfma_f32_16x16x32_bf16(af0, bf, acc[0][nt], 0, 0, 0);
        acc[1][nt] = __builtin_amdgcn_mfma_f32_16x16x32_bf16(af1, bf, acc[1][nt], 0, 0, 0);
      }
    }
  }
  float* outp = Sp + ((size_t)(p*BATCH + b) << 14);   // 128*128 tile
  #pragma unroll
  for (int mt = 0; mt < 2; ++mt)
    #pragma unroll
    for (int nt = 0; nt < 8; ++nt)
      #pragma unroll
      for (int r = 0; r < 4; ++r) {
        int c = w*32 + mt*16 + quad*4 + r;
        int d = nt*16 + id;
        outp[c*CH + d] = acc[mt][nt][r];
      }
}

// reduce split-K partials + softmax over last axis, scale 1/64 → Sch
__global__ __launch_bounds__(64) void chsoftmax_kernel(const float* __restrict__ Sp,
                                                       float* __restrict__ S) {
  int row = blockIdx.x;                    // b*128 + c
  int b = row >> 7, c = row & 127;
  int t = threadIdx.x;
  float s0 = 0.f, s1 = 0.f;
  #pragma unroll 4
  for (int p = 0; p < KCHUNKS; ++p) {
    const float* r = Sp + (((size_t)(p*BATCH + b) << 7) + c)*CH;
    s0 += r[t]; s1 += r[t+64];
  }
  const float sc = 1.f/64.f;
  s0 *= sc; s1 *= sc;
  float m = fmaxf(s0, s1);
  for (int off = 32; off; off >>= 1) m = fmaxf(m, __shfl_xor(m, off, 64));
  float p0 = __expf(s0 - m), p1 = __expf(s1 - m);
  float s = p0 + p1;
  for (int off = 32; off; off >>= 1) s += __shfl_xor(s, off, 64);
  float inv = 1.f/s;
  float* r = S + (size_t)row*CH;
  r[t]    = p0*inv;
  r[t+64] = p1*inv;
}

// ---------------- MFMA flash attention: 64 Q rows/block, 4 waves x 16 rows ----------------
__global__ __launch_bounds__(256) void flash_mfma_kernel(
    const unsigned short* __restrict__ Qg, const unsigned short* __restrict__ Kg,
    const unsigned short* __restrict__ Vg, float* __restrict__ Og) {
  __shared__ unsigned short Ks[64][136];
  __shared__ unsigned short Vt[128][72];
  __shared__ unsigned short Ps[4][16][72];

  int t = threadIdx.x;
  int lane = t & 63;
  int w = t >> 6;
  int id = lane & 15;
  int quad = lane >> 4;

  int b  = blockIdx.x >> 6;
  int n0 = (blockIdx.x & 63) << 6;

  const unsigned short* Qb = Qg + (size_t)b*NSP*CH;
  const unsigned short* Kb = Kg + (size_t)b*NSP*CH;
  const unsigned short* Vb = Vg + (size_t)b*NSP*CH;

  short8 qf[4];
  {
    const unsigned short* qp = Qb + (size_t)(n0 + w*16 + id)*CH + quad*8;
    #pragma unroll
    for (int kc = 0; kc < 4; ++kc) qf[kc] = *(const short8*)(qp + kc*32);
  }

  float mrun[4], lrun[4];
  #pragma unroll
  for (int r = 0; r < 4; ++r) { mrun[r] = -1e30f; lrun[r] = 0.f; }
  floatx4 Oacc[8];
  #pragma unroll
  for (int ct = 0; ct < 8; ++ct) Oacc[ct] = (floatx4){0.f,0.f,0.f,0.f};

  const float scale = 0.08838834764831845f;

  for (int kt = 0; kt < 64; ++kt) {
    int kbase = kt << 6;
    __syncthreads();
    for (int i = t; i < 1024; i += 256) {
      int r = i >> 4, c8 = (i & 15) << 3;
      *(short8*)&Ks[r][c8] = *(const short8*)(Kb + (size_t)(kbase + r)*CH + c8);
    }
    #pragma unroll
    for (int it = 0; it < 4; ++it) {
      int task = t + it*256;
      int c = task & 127, r0 = (task >> 7) << 3;
      short8 vv;
      #pragma unroll
      for (int j = 0; j < 8; ++j)
        vv[j] = (short)Vb[(size_t)(kbase + r0 + j)*CH + c];
      *(short8*)&Vt[c][r0] = vv;
    }
    __syncthreads();

    floatx4 S[4];
    #pragma unroll
    for (int nt = 0; nt < 4; ++nt) {
      floatx4 acc = (floatx4){0.f,0.f,0.f,0.f};
      #pragma unroll
      for (int kc = 0; kc < 4; ++kc) {
        short8 kf = *(const short8*)&Ks[nt*16 + id][kc*32 + quad*8];
        acc = __builtin_amdgcn_mfma_f32_16x16x32_bf16(qf[kc], kf, acc, 0, 0, 0);
      }
      S[nt] = acc;
    }

    float sv[4][4], m4[4];
    #pragma unroll
    for (int r = 0; r < 4; ++r) {
      #pragma unroll
      for (int nt = 0; nt < 4; ++nt) sv[nt][r] = S[nt][r] * scale;
      m4[r] = fmaxf(fmaxf(sv[0][r], sv[1][r]), fmaxf(sv[2][r], sv[3][r]));
    }
    #pragma unroll
    for (int off = 1; off <= 8; off <<= 1)
      #pragma unroll
      for (int r = 0; r < 4; ++r) m4[r] = fmaxf(m4[r], __shfl_xor(m4[r], off, 64));
    float alpha[4];
    #pragma unroll
    for (int r = 0; r < 4; ++r) {
      float mn = fmaxf(mrun[r], m4[r]);
      alpha[r] = __expf(mrun[r] - mn);
      mrun[r] = mn;
    }
    float rs[4] = {0.f,0.f,0.f,0.f};
    float pv[4][4];
    #pragma unroll
    for (int nt = 0; nt < 4; ++nt)
      #pragma unroll
      for (int r = 0; r < 4; ++r) {
        float p = __expf(sv[nt][r] - mrun[r]);
        pv[nt][r] = p; rs[r] += p;
      }
    #pragma unroll
    for (int off = 1; off <= 8; off <<= 1)
      #pragma unroll
      for (int r = 0; r < 4; ++r) rs[r] += __shfl_xor(rs[r], off, 64);
    #pragma unroll
    for (int r = 0; r < 4; ++r) lrun[r] = lrun[r]*alpha[r] + rs[r];

    #pragma unroll
    for (int nt = 0; nt < 4; ++nt)
      #pragma unroll
      for (int r = 0; r < 4; ++r)
        Ps[w][quad*4 + r][nt*16 + id] = f2bu(pv[nt][r]);

    #pragma unroll
    for (int ct = 0; ct < 8; ++ct)
      #pragma unroll
      for (int r = 0; r < 4; ++r) Oacc[ct][r] *= alpha[r];

    #pragma unroll
    for (int nc = 0; nc < 2; ++nc) {
      short8 pf = *(const short8*)&Ps[w][id][nc*32 + quad*8];
      #pragma unroll
      for (int ct = 0; ct < 8; ++ct) {
        short8 vf = *(const short8*)&Vt[ct*16 + id][nc*32 + quad*8];
        Oacc[ct] = __builtin_amdgcn_mfma_f32_16x16x32_bf16(pf, vf, Oacc[ct], 0, 0, 0);
      }
    }
  }

  float inv[4];
  #pragma unroll
  for (int r = 0; r < 4; ++r) inv[r] = 1.f / lrun[r];
  #pragma unroll
  for (int ct = 0; ct < 8; ++ct)
    #pragma unroll
    for (int r = 0; r < 4; ++r) {
      int row = n0 + w*16 + quad*4 + r;
      Og[(size_t)(b*NSP + row)*CH + ct*16 + id] = Oacc[ct][r] * inv[r];
    }
}

// ---------------- output = x + (w0*out_causal + w2*out_channel)^T ----------------
__global__ __launch_bounds__(256) void fuse_kernel(const float* __restrict__ x,
    const float* __restrict__ oc, const float* __restrict__ och,
    const float* __restrict__ wgt, float* __restrict__ out) {
  __shared__ float T[128][65];
  int t = threadIdx.x;
  int b  = blockIdx.x >> 6;
  int n0 = (blockIdx.x & 63) << 6;
  float w0 = wgt[b*3 + 0], w2 = wgt[b*3 + 2];
  const float* ocb  = oc  + (size_t)(b*NSP + n0)*CH;
  const float* ochb = och + (size_t)(b*NSP + n0)*CH;
  for (int i = t; i < 8192; i += 256) {
    int n = i >> 7, c = i & 127;
    T[c][n] = w0*ocb[(size_t)n*CH + c] + w2*ochb[(size_t)n*CH + c];
  }
  __syncthreads();
  for (int i = t; i < 8192; i += 256) {
    int c = i >> 6, n = i & 63;
    size_t idx = (size_t)(b*CH + c)*NSP + n0 + n;
    out[idx] = x[idx] + T[c][n];
  }
}

extern "C" void kernel_launch(void* const* d_in, const int* in_sizes, int n_in,
                              void* d_out, int out_size, void* d_ws, size_t ws_size,
                              hipStream_t stream) {
  (void)in_sizes; (void)n_in; (void)out_size; (void)ws_size;
  const float* x     = (const float*)d_in[0];
  const float* ln_g  = (const float*)d_in[1];
  const float* ln_b  = (const float*)d_in[2];
  const float* Wq    = (const float*)d_in[3];
  const float* bq    = (const float*)d_in[4];
  const float* Wk    = (const float*)d_in[5];
  const float* bk    = (const float*)d_in[6];
  const float* Wvc   = (const float*)d_in[7];
  const float* bvc   = (const float*)d_in[8];
  const float* Wvch  = (const float*)d_in[9];
  const float* bvch  = (const float*)d_in[10];
  const float* Wconv = (const float*)d_in[11];
  const float* bconv = (const float*)d_in[12];
  const float* Wg    = (const float*)d_in[13];
  const float* bg    = (const float*)d_in[14];

  float* out = (float*)d_out;
  float* cgf = out + (size_t)BIG;

  float* ws   = (float*)d_ws;
  float* xf   = ws;                          // fp32; reused as out_causal
  float* vch  = ws + (size_t)BIG;            // fp32; reused in-place as out_channel
  float* Sp   = ws + 2*(size_t)BIG;          // (KCHUNKS,B,128,128) fp32 partials
  float* Sch  = Sp + (size_t)KCHUNKS*BATCH*CH*CH;  // (B,128,128)
  float* pooled = Sch + BATCH*CH*CH;         // (B,128)
  float* wgt    = pooled + BATCH*CH;         // (B,3)
  unsigned short* qb  = (unsigned short*)(wgt + 16);  // bf16 buffers
  unsigned short* kb  = qb + (size_t)BIG;
  unsigned short* vcb = kb + (size_t)BIG;

  ln_kernel     <<<256, 256, 0, stream>>>(x, ln_g, ln_b, xf);
  pooled_kernel <<<512, 256, 0, stream>>>(x, pooled);
  gate_kernel   <<<1,   64,  0, stream>>>(pooled, Wg, bg, wgt);
  conv_kernel   <<<128, 256, 0, stream>>>(xf, Wconv, bconv, cgf);
  proj_kernel   <<<dim3(256,4), 256, 0, stream>>>(xf, Wq,bq, Wk,bk, Wvc,bvc, Wvch,bvch,
                                                  qb, kb, vcb, vch);
  chscore_kernel<<<dim3(KCHUNKS, BATCH), 256, 0, stream>>>(qb, kb, Sp);
  chsoftmax_kernel<<<512, 64, 0, stream>>>(Sp, Sch);
  flash_mfma_kernel<<<256, 256, 0, stream>>>(qb, kb, vcb, xf /*out_causal*/);
  chout_kernel  <<<256, 256, 0, stream>>>(vch, Sch);
  fuse_kernel   <<<256, 256, 0, stream>>>(x, xf, vch, wgt, out);
}